// Round 1
// baseline (214.294 us; speedup 1.0000x reference)
//
#include <hip/hip_runtime.h>
#include <cmath>

// GAT layer: N=4096 nodes, FIN=128, F=64 per head, H=8 heads.
// Pipeline:
//   k0: pack A (int32 dense) -> 64-bit masks (2 MB)
//   k1: feats = X @ W[h] (fp32), s_self/s_neigh dots, feats -> f16 in MFMA
//       B-fragment-swizzled layout
//   k2: fused masked-softmax (no max pass; exp(score-4) in f16 range) + PV
//       via v_mfma_f32_16x16x32_f16, normalize + bias + ELU epilogue.

#define NN 4096
#define FIN 128
#define FF 64
#define HH 8

typedef _Float16 half8 __attribute__((ext_vector_type(8)));
typedef _Float16 half4 __attribute__((ext_vector_type(4)));
typedef float f32x4 __attribute__((ext_vector_type(4)));

// ---------------------------------------------------------------- kernel 0
// One block per row; 4 waves, each packs 16 of the 64 u64 words of the row.
__global__ __launch_bounds__(256) void pack_kernel(
    const int* __restrict__ A, unsigned long long* __restrict__ bits) {
  const int row = blockIdx.x;
  const int wave = threadIdx.x >> 6, lane = threadIdx.x & 63;
  const int* ar = A + (size_t)row * NN;
  for (int w = wave; w < 64; w += 4) {
    int v = ar[(w << 6) + lane];
    unsigned long long m = __ballot(v != 0);
    if (lane == 0) bits[(row << 6) + w] = m;
  }
}

// ---------------------------------------------------------------- kernel 1
// grid (64 rowblocks, 8 heads), 256 threads. 64 rows x 64 cols per block,
// K=128 in two LDS phases. Epilogue: s_self/s_neigh dots (fp32, shfl-reduce)
// and f16 store in MFMA B-fragment order:
//   feats_sw[ ((h*128 + node/32)*4 + feat/16)*512 + (quad*16 + feat%16)*8 + node%8 ]
//   with quad = (node%32)/8.
__global__ __launch_bounds__(256) void feats_kernel(
    const float* __restrict__ X, const float* __restrict__ W,
    const float* __restrict__ a_self, const float* __restrict__ a_neigh,
    _Float16* __restrict__ feats_sw, float* __restrict__ s_self,
    float* __restrict__ s_neigh) {
  const int h = blockIdx.y, r0 = blockIdx.x * 64;
  __shared__ float Wl[128][68];  // pad 68: spread banks for k-varying reads
  __shared__ float Xl[64][68];
  const int tid = threadIdx.x, tx = tid & 15, ty = tid >> 4;

  f32x4 acc4[4];
#pragma unroll
  for (int i = 0; i < 4; ++i) acc4[i] = (f32x4){0.f, 0.f, 0.f, 0.f};

  for (int idx = tid; idx < 128 * 16; idx += 256) {
    int k = idx >> 4, c4 = (idx & 15) << 2;
    *(f32x4*)&Wl[k][c4] = *(const f32x4*)(W + (size_t)(h * FIN + k) * FF + c4);
  }
  for (int p = 0; p < 2; ++p) {
    __syncthreads();
    for (int idx = tid; idx < 64 * 16; idx += 256) {
      int r = idx >> 4, c4 = (idx & 15) << 2;
      *(f32x4*)&Xl[r][c4] =
          *(const f32x4*)(X + (size_t)(r0 + r) * FIN + p * 64 + c4);
    }
    __syncthreads();
    for (int kk = 0; kk < 64; ++kk) {
      f32x4 wv = *(const f32x4*)&Wl[p * 64 + kk][tx << 2];
#pragma unroll
      for (int i = 0; i < 4; ++i) {
        float x = Xl[(ty << 2) + i][kk];
        acc4[i] += x * wv;
      }
    }
  }

  // attention-coefficient dots (fp32 precision)
  float as4[4], an4[4];
#pragma unroll
  for (int jj = 0; jj < 4; ++jj) {
    as4[jj] = a_self[h * FF + (tx << 2) + jj];
    an4[jj] = a_neigh[h * FF + (tx << 2) + jj];
  }
#pragma unroll
  for (int i = 0; i < 4; ++i) {
    float ps = acc4[i][0] * as4[0] + acc4[i][1] * as4[1] +
               acc4[i][2] * as4[2] + acc4[i][3] * as4[3];
    float pn = acc4[i][0] * an4[0] + acc4[i][1] * an4[1] +
               acc4[i][2] * an4[2] + acc4[i][3] * an4[3];
#pragma unroll
    for (int m = 1; m <= 8; m <<= 1) {
      ps += __shfl_xor(ps, m, 64);
      pn += __shfl_xor(pn, m, 64);
    }
    if (tx == 0) {
      s_self[h * NN + r0 + (ty << 2) + i] = ps;
      s_neigh[h * NN + r0 + (ty << 2) + i] = pn;
    }
  }

  // f16 swizzled store: this thread's rows are 4 consecutive (4-aligned) ->
  // same quad, consecutive j; pack 4 rows per col into one 8B store.
  const int kb = (r0 + (ty << 2)) >> 5;
  const int quad = (ty >> 1) & 3;
  const int jbase = (ty & 1) << 2;
  const int nb = tx >> 2;
#pragma unroll
  for (int jj = 0; jj < 4; ++jj) {
    half4 v;
#pragma unroll
    for (int i = 0; i < 4; ++i) v[i] = (_Float16)acc4[i][jj];
    int l16 = ((tx & 3) << 2) + jj;
    size_t off = ((size_t)((h * 128 + kb) * 4 + nb) << 9) +
                 ((quad * 16 + l16) << 3) + jbase;
    *(half4*)(feats_sw + off) = v;
  }
}

// ---------------------------------------------------------------- kernel 2
// grid (128 rowblocks of 32, 8 heads), 256 threads = 4 waves.
// Each wave covers column tiles ct = wave, wave+4, ... (BN=64 each),
// accumulating partial numerator (MFMA f16) + partial denominator (fp32).
// Epilogue: cross-wave LDS reduce, divide, +bias, ELU, store.
__global__ __launch_bounds__(256, 4) void attn_kernel(
    const unsigned long long* __restrict__ Abits,
    const _Float16* __restrict__ feats_sw, const float* __restrict__ s_self,
    const float* __restrict__ s_neigh, const float* __restrict__ bias,
    float* __restrict__ out) {
  const int h = blockIdx.y, n0 = blockIdx.x << 5;
  const int tid = threadIdx.x, wave = tid >> 6, lane = tid & 63;
  const int l16 = lane & 15, quad = lane >> 4;

  const float ss0 = s_self[h * NN + n0 + l16];
  const float ss1 = s_self[h * NN + n0 + 16 + l16];

  f32x4 acc[2][4];
#pragma unroll
  for (int rf = 0; rf < 2; ++rf)
#pragma unroll
    for (int nb = 0; nb < 4; ++nb) acc[rf][nb] = (f32x4){0.f, 0.f, 0.f, 0.f};
  float dsum0 = 0.f, dsum1 = 0.f;

  const unsigned long long* ab0 = Abits + ((size_t)(n0 + l16) << 6);
  const unsigned long long* ab1 = ab0 + (16 << 6);
  const float* snh = s_neigh + h * NN + (quad << 3);
  const _Float16* fb = feats_sw + ((size_t)(h * 128) << 11) + (lane << 3);

#pragma unroll 1
  for (int ct = wave; ct < 64; ct += 4) {
    unsigned long long bits0 = ab0[ct];
    unsigned long long bits1 = ab1[ct];
    const float* sn = snh + (ct << 6);
    const _Float16* fbt = fb + (ct << 12);  // ct*2 kb's * 2048
#pragma unroll
    for (int kf = 0; kf < 2; ++kf) {
      f32x4 sa = *(const f32x4*)(sn + kf * 32);
      f32x4 sb = *(const f32x4*)(sn + kf * 32 + 4);
      const _Float16* fk = fbt + kf * 2048;
      half8 B0 = *(const half8*)(fk);
      half8 B1 = *(const half8*)(fk + 512);
      half8 B2 = *(const half8*)(fk + 1024);
      half8 B3 = *(const half8*)(fk + 1536);
      unsigned mb0 = (unsigned)((bits0 >> (kf * 32 + quad * 8)) & 0xFFull);
      unsigned mb1 = (unsigned)((bits1 >> (kf * 32 + quad * 8)) & 0xFFull);
      float snv[8];
#pragma unroll
      for (int jj = 0; jj < 4; ++jj) {
        snv[jj] = sa[jj];
        snv[4 + jj] = sb[jj];
      }
      half8 P0, P1;
#pragma unroll
      for (int j = 0; j < 8; ++j) {
        float t0 = ss0 + snv[j];
        t0 = fmaxf(t0, 0.2f * t0);
        float e0 = ((mb0 >> j) & 1) ? __expf(t0 - 4.0f) : 0.0f;
        dsum0 += e0;
        P0[j] = (_Float16)e0;
        float t1 = ss1 + snv[j];
        t1 = fmaxf(t1, 0.2f * t1);
        float e1 = ((mb1 >> j) & 1) ? __expf(t1 - 4.0f) : 0.0f;
        dsum1 += e1;
        P1[j] = (_Float16)e1;
      }
      acc[0][0] = __builtin_amdgcn_mfma_f32_16x16x32_f16(P0, B0, acc[0][0], 0, 0, 0);
      acc[0][1] = __builtin_amdgcn_mfma_f32_16x16x32_f16(P0, B1, acc[0][1], 0, 0, 0);
      acc[0][2] = __builtin_amdgcn_mfma_f32_16x16x32_f16(P0, B2, acc[0][2], 0, 0, 0);
      acc[0][3] = __builtin_amdgcn_mfma_f32_16x16x32_f16(P0, B3, acc[0][3], 0, 0, 0);
      acc[1][0] = __builtin_amdgcn_mfma_f32_16x16x32_f16(P1, B0, acc[1][0], 0, 0, 0);
      acc[1][1] = __builtin_amdgcn_mfma_f32_16x16x32_f16(P1, B1, acc[1][1], 0, 0, 0);
      acc[1][2] = __builtin_amdgcn_mfma_f32_16x16x32_f16(P1, B2, acc[1][2], 0, 0, 0);
      acc[1][3] = __builtin_amdgcn_mfma_f32_16x16x32_f16(P1, B3, acc[1][3], 0, 0, 0);
    }
  }

  // cross-wave reduction (pad 65 kills stride-64 bank aliasing)
  __shared__ float accL[4][32][65];
  __shared__ float denL[4][32];
#pragma unroll
  for (int rf = 0; rf < 2; ++rf)
#pragma unroll
    for (int nb = 0; nb < 4; ++nb)
#pragma unroll
      for (int r = 0; r < 4; ++r)
        accL[wave][rf * 16 + quad * 4 + r][nb * 16 + l16] = acc[rf][nb][r];
  float d0 = dsum0;
  d0 += __shfl_xor(d0, 16, 64);
  d0 += __shfl_xor(d0, 32, 64);
  float d1 = dsum1;
  d1 += __shfl_xor(d1, 16, 64);
  d1 += __shfl_xor(d1, 32, 64);
  if (quad == 0) {
    denL[wave][l16] = d0;
    denL[wave][16 + l16] = d1;
  }
  __syncthreads();

  const int row = tid >> 3, cg = (tid & 7) << 3;
  float dn = denL[0][row] + denL[1][row] + denL[2][row] + denL[3][row];
  float inv = 1.0f / dn;  // every row has a self loop -> dn > 0
  float* op = out + (size_t)(n0 + row) * (HH * FF) + h * FF + cg;
#pragma unroll
  for (int cc = 0; cc < 8; ++cc) {
    int c = cg + cc;
    float v = accL[0][row][c] + accL[1][row][c] + accL[2][row][c] +
              accL[3][row][c];
    v = v * inv + bias[h * FF + c];
    op[cc] = v > 0.f ? v : expm1f(v);
  }
}

// ---------------------------------------------------------------- launch
extern "C" void kernel_launch(void* const* d_in, const int* in_sizes, int n_in,
                              void* d_out, int out_size, void* d_ws,
                              size_t ws_size, hipStream_t stream) {
  const float* X = (const float*)d_in[0];
  const int* A = (const int*)d_in[1];
  const float* W = (const float*)d_in[2];
  const float* b = (const float*)d_in[3];
  const float* a_self = (const float*)d_in[4];
  const float* a_neigh = (const float*)d_in[5];
  float* out = (float*)d_out;

  char* ws = (char*)d_ws;
  unsigned long long* Abits = (unsigned long long*)ws;          // 2 MB
  _Float16* feats_sw = (_Float16*)(ws + (2u << 20));            // 4 MB
  float* s_self = (float*)(ws + (6u << 20));                    // 128 KB
  float* s_neigh = (float*)(ws + (6u << 20) + (128u << 10));    // 128 KB

  pack_kernel<<<NN, 256, 0, stream>>>(A, Abits);
  feats_kernel<<<dim3(64, 8), 256, 0, stream>>>(X, W, a_self, a_neigh,
                                                feats_sw, s_self, s_neigh);
  attn_kernel<<<dim3(128, 8), 256, 0, stream>>>(Abits, feats_sw, s_self,
                                                s_neigh, b, out);
}

// Round 2
// 170.282 us; speedup vs baseline: 1.2585x; 1.2585x over previous
//
#include <hip/hip_runtime.h>
#include <cmath>

// GAT layer: N=4096 nodes, FIN=128, F=64 per head, H=8 heads.
// Pipeline:
//   k0: pack A (int32 dense) -> 64-bit masks (2 MB)
//   k1: feats = X @ W[h] (fp32) -> f16 MFMA-B-swizzled; per-node factored
//       exponentials es=exp(s-2), esn=exp(0.2s-2), et=exp(t-2), etn=exp(0.2t-2)
//   k2: P[n,m] = mask * max(es_n*et_m, esn_n*etn_m)  (= exp(LReLU(s+t)-4),
//       exp monotone => max commutes) in packed f16; denominator via
//       v_dot2_f32_f16; PV via v_mfma_f32_16x16x32_f16; normalize+bias+ELU.

#define NN 4096
#define FIN 128
#define FF 64
#define HH 8

typedef _Float16 h2 __attribute__((ext_vector_type(2)));
typedef _Float16 h8 __attribute__((ext_vector_type(8)));
typedef _Float16 half4 __attribute__((ext_vector_type(4)));
typedef float f32x4 __attribute__((ext_vector_type(4)));

union H8 {
  h8 v;
  h2 p[4];
};

static __device__ __forceinline__ float dot2acc(h2 a, h2 b, float c) {
#if __has_builtin(__builtin_amdgcn_fdot2)
  return __builtin_amdgcn_fdot2(a, b, c, false);
#else
  return c + (float)a[0] * (float)b[0] + (float)a[1] * (float)b[1];
#endif
}

// ---------------------------------------------------------------- kernel 0
__global__ __launch_bounds__(256) void pack_kernel(
    const int* __restrict__ A, unsigned long long* __restrict__ bits) {
  const int row = blockIdx.x;
  const int wave = threadIdx.x >> 6, lane = threadIdx.x & 63;
  const int* ar = A + (size_t)row * NN;
  for (int w = wave; w < 64; w += 4) {
    int v = ar[(w << 6) + lane];
    unsigned long long m = __ballot(v != 0);
    if (lane == 0) bits[(row << 6) + w] = m;
  }
}

// ---------------------------------------------------------------- kernel 1
// grid (64 rowblocks, 8 heads), 256 threads. 64 rows x 64 cols per block,
// K=128 in two LDS phases. Epilogue: factored exponentials + f16 store in
// MFMA B-fragment order.
__global__ __launch_bounds__(256) void feats_kernel(
    const float* __restrict__ X, const float* __restrict__ W,
    const float* __restrict__ a_self, const float* __restrict__ a_neigh,
    _Float16* __restrict__ feats_sw, _Float16* __restrict__ es_h,
    _Float16* __restrict__ esn_h, _Float16* __restrict__ et_h,
    _Float16* __restrict__ etn_h) {
  const int h = blockIdx.y, r0 = blockIdx.x * 64;
  __shared__ float Wl[128][68];
  __shared__ float Xl[64][68];
  const int tid = threadIdx.x, tx = tid & 15, ty = tid >> 4;

  f32x4 acc4[4];
#pragma unroll
  for (int i = 0; i < 4; ++i) acc4[i] = (f32x4){0.f, 0.f, 0.f, 0.f};

  for (int idx = tid; idx < 128 * 16; idx += 256) {
    int k = idx >> 4, c4 = (idx & 15) << 2;
    *(f32x4*)&Wl[k][c4] = *(const f32x4*)(W + (size_t)(h * FIN + k) * FF + c4);
  }
  for (int p = 0; p < 2; ++p) {
    __syncthreads();
    for (int idx = tid; idx < 64 * 16; idx += 256) {
      int r = idx >> 4, c4 = (idx & 15) << 2;
      *(f32x4*)&Xl[r][c4] =
          *(const f32x4*)(X + (size_t)(r0 + r) * FIN + p * 64 + c4);
    }
    __syncthreads();
    for (int kk = 0; kk < 64; ++kk) {
      f32x4 wv = *(const f32x4*)&Wl[p * 64 + kk][tx << 2];
#pragma unroll
      for (int i = 0; i < 4; ++i) {
        float x = Xl[(ty << 2) + i][kk];
        acc4[i] += x * wv;
      }
    }
  }

  float as4[4], an4[4];
#pragma unroll
  for (int jj = 0; jj < 4; ++jj) {
    as4[jj] = a_self[h * FF + (tx << 2) + jj];
    an4[jj] = a_neigh[h * FF + (tx << 2) + jj];
  }
#pragma unroll
  for (int i = 0; i < 4; ++i) {
    float ps = acc4[i][0] * as4[0] + acc4[i][1] * as4[1] +
               acc4[i][2] * as4[2] + acc4[i][3] * as4[3];
    float pn = acc4[i][0] * an4[0] + acc4[i][1] * an4[1] +
               acc4[i][2] * an4[2] + acc4[i][3] * an4[3];
#pragma unroll
    for (int m = 1; m <= 8; m <<= 1) {
      ps += __shfl_xor(ps, m, 64);
      pn += __shfl_xor(pn, m, 64);
    }
    if (tx == 0) {
      int node = h * NN + r0 + (ty << 2) + i;
      es_h[node] = (_Float16)__expf(ps - 2.0f);
      esn_h[node] = (_Float16)__expf(0.2f * ps - 2.0f);
      et_h[node] = (_Float16)__expf(pn - 2.0f);
      etn_h[node] = (_Float16)__expf(0.2f * pn - 2.0f);
    }
  }

  const int kb = (r0 + (ty << 2)) >> 5;
  const int quad = (ty >> 1) & 3;
  const int jbase = (ty & 1) << 2;
  const int nb = tx >> 2;
#pragma unroll
  for (int jj = 0; jj < 4; ++jj) {
    half4 v;
#pragma unroll
    for (int i = 0; i < 4; ++i) v[i] = (_Float16)acc4[i][jj];
    int l16 = ((tx & 3) << 2) + jj;
    size_t off = ((size_t)((h * 128 + kb) * 4 + nb) << 9) +
                 ((quad * 16 + l16) << 3) + jbase;
    *(half4*)(feats_sw + off) = v;
  }
}

// ---------------------------------------------------------------- kernel 2
// grid 512 = rb*8 + h  (id%8 == h -> one head per XCD: its 512 KB feats is
// L2-resident). 64 rows/block, 4 waves split column tiles (16 ct each).
// Inner loop fully packed-f16; mask expanded via 256-entry LDS LUT.
__global__ __launch_bounds__(256, 2) void attn_kernel(
    const unsigned long long* __restrict__ Abits,
    const _Float16* __restrict__ feats_sw, const _Float16* __restrict__ es_h,
    const _Float16* __restrict__ esn_h, const _Float16* __restrict__ et_h,
    const _Float16* __restrict__ etn_h, const float* __restrict__ bias,
    float* __restrict__ out) {
  const int bid = blockIdx.x;
  const int h = bid & 7, rb = bid >> 3;
  const int n0 = rb << 6;
  const int tid = threadIdx.x, wave = tid >> 6, lane = tid & 63;
  const int l16 = lane & 15, quad = lane >> 4;

  __shared__ h8 lut[256];
  __shared__ float accL[4][32][66];  // pad 66 -> conflict-free MFMA-row writes
  __shared__ float denL[4][64];
  {
    h8 m;
#pragma unroll
    for (int j = 0; j < 8; ++j) m[j] = (_Float16)((tid >> j) & 1);
    lut[tid] = m;
  }
  __syncthreads();

  h2 esp[4], esnp[4];
#pragma unroll
  for (int rg = 0; rg < 4; ++rg) {
    _Float16 e = es_h[h * NN + n0 + rg * 16 + l16];
    _Float16 en = esn_h[h * NN + n0 + rg * 16 + l16];
    esp[rg] = (h2){e, e};
    esnp[rg] = (h2){en, en};
  }

  f32x4 acc[4][4];
  float dsum[4] = {0.f, 0.f, 0.f, 0.f};
#pragma unroll
  for (int rg = 0; rg < 4; ++rg)
#pragma unroll
    for (int nb = 0; nb < 4; ++nb) acc[rg][nb] = (f32x4){0.f, 0.f, 0.f, 0.f};

  const uint2* ab = (const uint2*)Abits;
  const int rowbase = n0 + l16;
  const _Float16* etp = et_h + h * NN + (quad << 3);
  const _Float16* etnp = etn_h + h * NN + (quad << 3);
  const _Float16* fb = feats_sw + ((size_t)h << 18) + (lane << 3);

  for (int ct = wave; ct < 64; ct += 4) {
    uint2 bits[4];
#pragma unroll
    for (int rg = 0; rg < 4; ++rg)
      bits[rg] = ab[((rowbase + rg * 16) << 6) + ct];
    const _Float16* fbt = fb + (ct << 12);
#pragma unroll
    for (int kf = 0; kf < 2; ++kf) {
      H8 ET, ETN;
      ET.v = *(const h8*)(etp + (ct << 6) + kf * 32);
      ETN.v = *(const h8*)(etnp + (ct << 6) + kf * 32);
      const _Float16* fk = fbt + (kf << 11);
      h8 B0 = *(const h8*)(fk);
      h8 B1 = *(const h8*)(fk + 512);
      h8 B2 = *(const h8*)(fk + 1024);
      h8 B3 = *(const h8*)(fk + 1536);
#pragma unroll
      for (int rg = 0; rg < 4; ++rg) {
        unsigned word = kf ? bits[rg].y : bits[rg].x;
        unsigned byt = (word >> (quad << 3)) & 0xFFu;
        H8 mm;
        mm.v = lut[byt];
        H8 P;
#pragma unroll
        for (int p = 0; p < 4; ++p) {
          h2 a = esp[rg] * ET.p[p];
          h2 b = esnp[rg] * ETN.p[p];
          h2 r = __builtin_elementwise_max(a, b);
          h2 pm = r * mm.p[p];
          P.p[p] = pm;
          dsum[rg] = dot2acc(pm, (h2){(_Float16)1.f, (_Float16)1.f}, dsum[rg]);
        }
        acc[rg][0] =
            __builtin_amdgcn_mfma_f32_16x16x32_f16(P.v, B0, acc[rg][0], 0, 0, 0);
        acc[rg][1] =
            __builtin_amdgcn_mfma_f32_16x16x32_f16(P.v, B1, acc[rg][1], 0, 0, 0);
        acc[rg][2] =
            __builtin_amdgcn_mfma_f32_16x16x32_f16(P.v, B2, acc[rg][2], 0, 0, 0);
        acc[rg][3] =
            __builtin_amdgcn_mfma_f32_16x16x32_f16(P.v, B3, acc[rg][3], 0, 0, 0);
      }
    }
  }

  // denominator: reduce across quads, one slot per (wave, row)
#pragma unroll
  for (int rg = 0; rg < 4; ++rg) {
    float d = dsum[rg];
    d += __shfl_xor(d, 16, 64);
    d += __shfl_xor(d, 32, 64);
    if (quad == 0) denL[wave][rg * 16 + l16] = d;
  }

  const int lrow = tid >> 3, cgg = (tid & 7) << 3;
#pragma unroll
  for (int ph = 0; ph < 2; ++ph) {
    __syncthreads();
#pragma unroll
    for (int rg2 = 0; rg2 < 2; ++rg2) {
      int rg = ph * 2 + rg2;
#pragma unroll
      for (int nb = 0; nb < 4; ++nb)
#pragma unroll
        for (int r = 0; r < 4; ++r)
          accL[wave][rg2 * 16 + quad * 4 + r][nb * 16 + l16] = acc[rg][nb][r];
    }
    __syncthreads();
    const int row = ph * 32 + lrow;
    float dn = denL[0][row] + denL[1][row] + denL[2][row] + denL[3][row];
    float inv = 1.0f / dn;  // self loop -> dn > 0
    f32x4 r0, r1;
#pragma unroll
    for (int i = 0; i < 4; ++i) {
      r0[i] = accL[0][lrow][cgg + i] + accL[1][lrow][cgg + i] +
              accL[2][lrow][cgg + i] + accL[3][lrow][cgg + i];
      r1[i] = accL[0][lrow][cgg + 4 + i] + accL[1][lrow][cgg + 4 + i] +
              accL[2][lrow][cgg + 4 + i] + accL[3][lrow][cgg + 4 + i];
    }
    const f32x4 b0 = *(const f32x4*)(bias + h * FF + cgg);
    const f32x4 b1 = *(const f32x4*)(bias + h * FF + cgg + 4);
#pragma unroll
    for (int i = 0; i < 4; ++i) {
      float v0 = r0[i] * inv + b0[i];
      float v1 = r1[i] * inv + b1[i];
      r0[i] = v0 > 0.f ? v0 : expm1f(v0);
      r1[i] = v1 > 0.f ? v1 : expm1f(v1);
    }
    float* op = out + (size_t)(n0 + row) * (HH * FF) + h * FF + cgg;
    *(f32x4*)op = r0;
    *(f32x4*)(op + 4) = r1;
  }
}

// ---------------------------------------------------------------- launch
extern "C" void kernel_launch(void* const* d_in, const int* in_sizes, int n_in,
                              void* d_out, int out_size, void* d_ws,
                              size_t ws_size, hipStream_t stream) {
  const float* X = (const float*)d_in[0];
  const int* A = (const int*)d_in[1];
  const float* W = (const float*)d_in[2];
  const float* b = (const float*)d_in[3];
  const float* a_self = (const float*)d_in[4];
  const float* a_neigh = (const float*)d_in[5];
  float* out = (float*)d_out;

  char* ws = (char*)d_ws;
  unsigned long long* Abits = (unsigned long long*)ws;        // 2 MB
  _Float16* feats_sw = (_Float16*)(ws + (2u << 20));          // 4 MB
  _Float16* es_h = (_Float16*)(ws + (6u << 20));              // 64 KB
  _Float16* esn_h = (_Float16*)(ws + (6u << 20) + (64u << 10));
  _Float16* et_h = (_Float16*)(ws + (6u << 20) + (128u << 10));
  _Float16* etn_h = (_Float16*)(ws + (6u << 20) + (192u << 10));

  pack_kernel<<<NN, 256, 0, stream>>>(A, Abits);
  feats_kernel<<<dim3(64, 8), 256, 0, stream>>>(X, W, a_self, a_neigh,
                                                feats_sw, es_h, esn_h, et_h,
                                                etn_h);
  attn_kernel<<<512, 256, 0, stream>>>(Abits, feats_sw, es_h, esn_h, et_h,
                                       etn_h, b, out);
}

// Round 3
// 152.475 us; speedup vs baseline: 1.4054x; 1.1168x over previous
//
#include <hip/hip_runtime.h>
#include <cmath>

// GAT layer: N=4096 nodes, FIN=128, F=64 per head, H=8 heads.
// Pipeline:
//   k0: pack A (int32 dense) -> 64-bit masks (2 MB), 4 loads in flight
//   k1: feats = X @ W[h] via f16 MFMA (fp32 accum) -> f16 MFMA-B-swizzled;
//       factored exponentials es=exp(s-2), esn=exp(0.2s-2), et, etn (f16)
//   k2: P[n,m] = mask * max(es_n*et_m, esn_n*etn_m)  (= exp(LReLU(s+t)-4))
//       packed f16; mask via conflict-free 16-entry nibble LUT; denominator
//       via v_dot2_f32_f16; PV via v_mfma_f32_16x16x32_f16.
//       512-thr blocks (8 waves K-split) for 16 waves/CU latency hiding.

#define NN 4096
#define FIN 128
#define FF 64
#define HH 8

typedef _Float16 h2 __attribute__((ext_vector_type(2)));
typedef _Float16 h4 __attribute__((ext_vector_type(4)));
typedef _Float16 h8 __attribute__((ext_vector_type(8)));
typedef float f32x4 __attribute__((ext_vector_type(4)));

union H8 {
  h8 v;
  h2 p[4];
};
union H4 {
  h4 v;
  h2 p[2];
};

static __device__ __forceinline__ float dot2acc(h2 a, float c) {
#if __has_builtin(__builtin_amdgcn_fdot2)
  return __builtin_amdgcn_fdot2(a, (h2){(_Float16)1.f, (_Float16)1.f}, c,
                                false);
#else
  return c + (float)a[0] + (float)a[1];
#endif
}

// ---------------------------------------------------------------- kernel 0
// One block per row; each wave packs 16 words in 4 iters x 4 independent
// loads (MLP instead of load->ballot serial chain).
__global__ __launch_bounds__(256) void pack_kernel(
    const int* __restrict__ A, unsigned long long* __restrict__ bits) {
  const int row = blockIdx.x;
  const int wave = threadIdx.x >> 6, lane = threadIdx.x & 63;
  const int* ar = A + (size_t)row * NN;
#pragma unroll
  for (int g = 0; g < 4; ++g) {
    const int w0 = wave * 16 + g * 4;
    int v0 = ar[(w0 + 0) * 64 + lane];
    int v1 = ar[(w0 + 1) * 64 + lane];
    int v2 = ar[(w0 + 2) * 64 + lane];
    int v3 = ar[(w0 + 3) * 64 + lane];
    unsigned long long m0 = __ballot(v0 != 0);
    unsigned long long m1 = __ballot(v1 != 0);
    unsigned long long m2 = __ballot(v2 != 0);
    unsigned long long m3 = __ballot(v3 != 0);
    if (lane == 0) {
      bits[(row << 6) + w0 + 0] = m0;
      bits[(row << 6) + w0 + 1] = m1;
      bits[(row << 6) + w0 + 2] = m2;
      bits[(row << 6) + w0 + 3] = m3;
    }
  }
}

// ---------------------------------------------------------------- kernel 1
// grid (32 rowblocks, 8 heads), 256 threads = 4 waves.
// Block: 128 rows x 64 cols, K=128 via 4x mfma_f32_16x16x32_f16.
// Wave w: rows w*32..w*32+31 (2 row-frags), all 64 cols (4 col-frags).
__global__ __launch_bounds__(256) void feats_kernel(
    const float* __restrict__ X, const float* __restrict__ W,
    const float* __restrict__ a_self, const float* __restrict__ a_neigh,
    _Float16* __restrict__ feats_sw, _Float16* __restrict__ es_h,
    _Float16* __restrict__ esn_h, _Float16* __restrict__ et_h,
    _Float16* __restrict__ etn_h) {
  const int h = blockIdx.y, r0 = blockIdx.x * 128;
  const int tid = threadIdx.x, wave = tid >> 6, lane = tid & 63;
  const int l16 = lane & 15, quad = lane >> 4;

  __shared__ _Float16 Xh[128][136];  // pad 8 h16 -> balanced banks
  __shared__ _Float16 Wt[64][136];   // W transposed [f][k]

  // stage X -> f16
  for (int i = tid; i < 128 * 32; i += 256) {
    int row = i >> 5, c4 = (i & 31) << 2;
    f32x4 x = *(const f32x4*)(X + (size_t)(r0 + row) * FIN + c4);
    h4 hx = {(_Float16)x[0], (_Float16)x[1], (_Float16)x[2], (_Float16)x[3]};
    *(h4*)&Xh[row][c4] = hx;
  }
  // stage W^T -> f16
  for (int i = tid; i < 128 * 16; i += 256) {
    int k = i >> 4, f4 = (i & 15) << 2;
    f32x4 w = *(const f32x4*)(W + (size_t)(h * FIN + k) * FF + f4);
#pragma unroll
    for (int j = 0; j < 4; ++j) Wt[f4 + j][k] = (_Float16)w[j];
  }
  __syncthreads();

  f32x4 acc[2][4];
#pragma unroll
  for (int rg = 0; rg < 2; ++rg)
#pragma unroll
    for (int nb = 0; nb < 4; ++nb) acc[rg][nb] = (f32x4){0.f, 0.f, 0.f, 0.f};

#pragma unroll
  for (int kt = 0; kt < 4; ++kt) {
    const int kof = kt * 32 + quad * 8;
    h8 A0 = *(const h8*)&Xh[wave * 32 + l16][kof];
    h8 A1 = *(const h8*)&Xh[wave * 32 + 16 + l16][kof];
#pragma unroll
    for (int nb = 0; nb < 4; ++nb) {
      h8 B = *(const h8*)&Wt[nb * 16 + l16][kof];
      acc[0][nb] = __builtin_amdgcn_mfma_f32_16x16x32_f16(A0, B, acc[0][nb], 0, 0, 0);
      acc[1][nb] = __builtin_amdgcn_mfma_f32_16x16x32_f16(A1, B, acc[1][nb], 0, 0, 0);
    }
  }

  // attention-coefficient dots -> factored exponentials (f16)
  float as[4], an[4];
#pragma unroll
  for (int nb = 0; nb < 4; ++nb) {
    as[nb] = a_self[h * FF + nb * 16 + l16];
    an[nb] = a_neigh[h * FF + nb * 16 + l16];
  }
#pragma unroll
  for (int rg = 0; rg < 2; ++rg)
#pragma unroll
    for (int r = 0; r < 4; ++r) {
      float ps = acc[rg][0][r] * as[0] + acc[rg][1][r] * as[1] +
                 acc[rg][2][r] * as[2] + acc[rg][3][r] * as[3];
      float pn = acc[rg][0][r] * an[0] + acc[rg][1][r] * an[1] +
                 acc[rg][2][r] * an[2] + acc[rg][3][r] * an[3];
#pragma unroll
      for (int m = 1; m <= 8; m <<= 1) {
        ps += __shfl_xor(ps, m, 64);
        pn += __shfl_xor(pn, m, 64);
      }
      if (l16 == 0) {
        int node = h * NN + r0 + wave * 32 + rg * 16 + quad * 4 + r;
        es_h[node] = (_Float16)__expf(ps - 2.0f);
        esn_h[node] = (_Float16)__expf(0.2f * ps - 2.0f);
        et_h[node] = (_Float16)__expf(pn - 2.0f);
        etn_h[node] = (_Float16)__expf(0.2f * pn - 2.0f);
      }
    }

  // swizzled f16 store of feats (MFMA B-fragment order)
  const int kb = (r0 >> 5) + wave;  // node/32
  const int quad2base = quad >> 1;
  const int jbase = (quad & 1) << 2;
#pragma unroll
  for (int rg = 0; rg < 2; ++rg) {
    const int quad2 = rg * 2 + quad2base;
#pragma unroll
    for (int nb = 0; nb < 4; ++nb) {
      h4 v = {(_Float16)acc[rg][nb][0], (_Float16)acc[rg][nb][1],
              (_Float16)acc[rg][nb][2], (_Float16)acc[rg][nb][3]};
      size_t off = ((size_t)((h * 128 + kb) * 4 + nb) << 9) +
                   ((quad2 * 16 + l16) << 3) + jbase;
      *(h4*)(feats_sw + off) = v;
    }
  }
}

// ---------------------------------------------------------------- kernel 2
// grid 512 = rb*8 + h (one head per XCD -> 512 KB feats L2-resident).
// 64 rows/block, 512 threads = 8 waves splitting the 64 column tiles.
__global__ __launch_bounds__(512, 4) void attn_kernel(
    const unsigned long long* __restrict__ Abits,
    const _Float16* __restrict__ feats_sw, const _Float16* __restrict__ es_h,
    const _Float16* __restrict__ esn_h, const _Float16* __restrict__ et_h,
    const _Float16* __restrict__ etn_h, const float* __restrict__ bias,
    float* __restrict__ out) {
  const int bid = blockIdx.x;
  const int h = bid & 7, n0 = (bid >> 3) << 6;
  const int tid = threadIdx.x, wave = tid >> 6, lane = tid & 63;
  const int l16 = lane & 15, quad = lane >> 4;

  __shared__ h4 lut16[16];           // 16 x 8B = exactly 32 banks: no conflicts
  __shared__ float accL[8][32][66];  // 66 KB, epilogue only
  __shared__ float denL[8][64];
  if (tid < 16) {
    h4 m;
#pragma unroll
    for (int j = 0; j < 4; ++j) m[j] = (_Float16)((tid >> j) & 1);
    lut16[tid] = m;
  }
  __syncthreads();

  h2 esp[4], esnp[4];
#pragma unroll
  for (int rg = 0; rg < 4; ++rg) {
    _Float16 e = es_h[h * NN + n0 + rg * 16 + l16];
    _Float16 en = esn_h[h * NN + n0 + rg * 16 + l16];
    esp[rg] = (h2){e, e};
    esnp[rg] = (h2){en, en};
  }

  f32x4 acc[4][4];
  float dsum[4] = {0.f, 0.f, 0.f, 0.f};
#pragma unroll
  for (int rg = 0; rg < 4; ++rg)
#pragma unroll
    for (int nb = 0; nb < 4; ++nb) acc[rg][nb] = (f32x4){0.f, 0.f, 0.f, 0.f};

  const uint2* ab = (const uint2*)Abits;
  const int rowbase = n0 + l16;
  const _Float16* etp = et_h + h * NN + (quad << 3);
  const _Float16* etnp = etn_h + h * NN + (quad << 3);
  const _Float16* fb = feats_sw + ((size_t)h << 18) + (lane << 3);

  for (int ct = wave; ct < 64; ct += 8) {
    uint2 bits[4];
#pragma unroll
    for (int rg = 0; rg < 4; ++rg)
      bits[rg] = ab[((rowbase + rg * 16) << 6) + ct];
    const _Float16* fbt = fb + (ct << 12);
#pragma unroll
    for (int kf = 0; kf < 2; ++kf) {
      H8 ET, ETN;
      ET.v = *(const h8*)(etp + (ct << 6) + kf * 32);
      ETN.v = *(const h8*)(etnp + (ct << 6) + kf * 32);
      const _Float16* fk = fbt + (kf << 11);
      h8 B0 = *(const h8*)(fk);
      h8 B1 = *(const h8*)(fk + 512);
      h8 B2 = *(const h8*)(fk + 1024);
      h8 B3 = *(const h8*)(fk + 1536);
#pragma unroll
      for (int rg = 0; rg < 4; ++rg) {
        unsigned word = kf ? bits[rg].y : bits[rg].x;
        unsigned byt = (word >> (quad << 3)) & 0xFFu;
        H4 mlo, mhi;
        mlo.v = lut16[byt & 15u];
        mhi.v = lut16[byt >> 4];
        H8 P;
#pragma unroll
        for (int p = 0; p < 4; ++p) {
          h2 a = esp[rg] * ET.p[p];
          h2 b = esnp[rg] * ETN.p[p];
          h2 r = __builtin_elementwise_max(a, b);
          h2 pm = r * (p < 2 ? mlo.p[p] : mhi.p[p - 2]);
          P.p[p] = pm;
          dsum[rg] = dot2acc(pm, dsum[rg]);
        }
        acc[rg][0] =
            __builtin_amdgcn_mfma_f32_16x16x32_f16(P.v, B0, acc[rg][0], 0, 0, 0);
        acc[rg][1] =
            __builtin_amdgcn_mfma_f32_16x16x32_f16(P.v, B1, acc[rg][1], 0, 0, 0);
        acc[rg][2] =
            __builtin_amdgcn_mfma_f32_16x16x32_f16(P.v, B2, acc[rg][2], 0, 0, 0);
        acc[rg][3] =
            __builtin_amdgcn_mfma_f32_16x16x32_f16(P.v, B3, acc[rg][3], 0, 0, 0);
      }
    }
  }

  // denominator partials per wave
#pragma unroll
  for (int rg = 0; rg < 4; ++rg) {
    float d = dsum[rg];
    d += __shfl_xor(d, 16, 64);
    d += __shfl_xor(d, 32, 64);
    if (quad == 0) denL[wave][rg * 16 + l16] = d;
  }

  // epilogue in 2 phases of 32 rows: 8-way cross-wave reduce
  const int erow = tid >> 4, ec0 = (tid & 15) << 2;
#pragma unroll
  for (int ph = 0; ph < 2; ++ph) {
    __syncthreads();
#pragma unroll
    for (int rg2 = 0; rg2 < 2; ++rg2) {
      int rg = ph * 2 + rg2;
#pragma unroll
      for (int nb = 0; nb < 4; ++nb)
#pragma unroll
        for (int r = 0; r < 4; ++r)
          accL[wave][rg2 * 16 + quad * 4 + r][nb * 16 + l16] = acc[rg][nb][r];
    }
    __syncthreads();
    const int grow = ph * 32 + erow;
    float dn = 0.f;
#pragma unroll
    for (int w = 0; w < 8; ++w) dn += denL[w][grow];
    float inv = 1.0f / dn;  // self loop -> dn > 0
    f32x4 v = (f32x4){0.f, 0.f, 0.f, 0.f};
#pragma unroll
    for (int w = 0; w < 8; ++w) {
      f32x4 t = *(const f32x4*)&accL[w][erow][ec0];
      v += t;
    }
    const f32x4 bv = *(const f32x4*)(bias + h * FF + ec0);
#pragma unroll
    for (int i = 0; i < 4; ++i) {
      float x = v[i] * inv + bv[i];
      v[i] = x > 0.f ? x : (__expf(x) - 1.0f);
    }
    float* op = out + (size_t)(n0 + grow) * (HH * FF) + h * FF + ec0;
    *(f32x4*)op = v;
  }
}

// ---------------------------------------------------------------- launch
extern "C" void kernel_launch(void* const* d_in, const int* in_sizes, int n_in,
                              void* d_out, int out_size, void* d_ws,
                              size_t ws_size, hipStream_t stream) {
  const float* X = (const float*)d_in[0];
  const int* A = (const int*)d_in[1];
  const float* W = (const float*)d_in[2];
  const float* b = (const float*)d_in[3];
  const float* a_self = (const float*)d_in[4];
  const float* a_neigh = (const float*)d_in[5];
  float* out = (float*)d_out;

  char* ws = (char*)d_ws;
  unsigned long long* Abits = (unsigned long long*)ws;        // 2 MB
  _Float16* feats_sw = (_Float16*)(ws + (2u << 20));          // 4 MB
  _Float16* es_h = (_Float16*)(ws + (6u << 20));              // 64 KB
  _Float16* esn_h = (_Float16*)(ws + (6u << 20) + (64u << 10));
  _Float16* et_h = (_Float16*)(ws + (6u << 20) + (128u << 10));
  _Float16* etn_h = (_Float16*)(ws + (6u << 20) + (192u << 10));

  pack_kernel<<<NN, 256, 0, stream>>>(A, Abits);
  feats_kernel<<<dim3(32, 8), 256, 0, stream>>>(X, W, a_self, a_neigh,
                                                feats_sw, es_h, esn_h, et_h,
                                                etn_h);
  attn_kernel<<<512, 512, 0, stream>>>(Abits, feats_sw, es_h, esn_h, et_h,
                                       etn_h, b, out);
}